// Round 13
// baseline (43.272 us; speedup 1.0000x reference)
//
#include <hip/hip_runtime.h>
#include <hip/hip_fp16.h>

#define NN   2048
#define FIN  128
#define FOUT 64
#define LOG2E 1.44269504088896f

using f16x8  = __attribute__((ext_vector_type(8))) _Float16;
using f16x4  = __attribute__((ext_vector_type(4))) _Float16;
using f16x2  = __attribute__((ext_vector_type(2))) _Float16;
using f32x4  = __attribute__((ext_vector_type(4))) float;
using f32x16 = __attribute__((ext_vector_type(16))) float;
using i32x4  = __attribute__((ext_vector_type(4))) int;

__device__ inline float fast_exp2(float x) {
#if __has_builtin(__builtin_amdgcn_exp2f)
    return __builtin_amdgcn_exp2f(x);
#else
    return exp2f(x);
#endif
}
__device__ inline float fast_rcp(float x) {
#if __has_builtin(__builtin_amdgcn_rcpf)
    return __builtin_amdgcn_rcpf(x);
#else
    return 1.0f / x;
#endif
}
__device__ inline float fast_tanh(float x) {
    float e = fast_exp2(2.0f * LOG2E * x);
    return 1.0f - 2.0f * fast_rcp(e + 1.0f);
}
__device__ inline unsigned cvt2h(float a, float b) {
    return __builtin_bit_cast(unsigned, __builtin_amdgcn_cvt_pkrtz(a, b));
}
__device__ inline f16x2 pkmax(f16x2 a, f16x2 b) {
#if __has_builtin(__builtin_elementwise_max)
    return __builtin_elementwise_max(a, b);
#else
    f16x2 r; r[0] = a[0] > b[0] ? a[0] : b[0]; r[1] = a[1] > b[1] ? a[1] : b[1];
    return r;
#endif
}
__device__ inline unsigned bmask(unsigned wb, int p) {
    unsigned lo = (unsigned)(-(int)((wb >> (2 * p)) & 1u));
    unsigned hi = (unsigned)(-(int)((wb >> (2 * p + 1)) & 1u));
    return (hi & 0xFFFF0000u) | (lo & 0x0000FFFFu);
}

// h16B layout (32x32x16 B-frag order), per (bh):
//   off = bh*131072 + (j>>4)*1024 + (o>>5)*512 + ((o&31) + 32*((j>>3)&1))*8 + (j&7)
// i.e. per 16-j block, per 32-col tile: lane = col + 32*kgroup, elem i = j&7.
// adjbits (ROW-MAJOR dense): [flat_row(8192)][wc(64)] u32

// ---------------------------------------------------------------------------
// Kernel 1: MFMA projection + fast-tanh s_src/s_dst (log2e-scaled) +
// h -> fp16 (32x32 B-frag order) + adj bitpack. 512 blocks x 256 threads.
// ---------------------------------------------------------------------------
__global__ __launch_bounds__(256) void k1_proj(
    const float* __restrict__ x, const float* __restrict__ w,
    const float* __restrict__ a_src, const float* __restrict__ a_dst,
    const int* __restrict__ adj,
    _Float16* __restrict__ h16B, float* __restrict__ ssrc, float* __restrict__ sdst,
    unsigned int* __restrict__ adjbits)
{
    __shared__ __align__(16) _Float16 xf[8192];   // A-frags (16x16x32 path)
    __shared__ __align__(16) _Float16 wf[8192];   // B-frags

    const int t    = threadIdx.x;
    const int bx   = blockIdx.x;
    const int bh   = bx >> 5;
    const int tile = bx & 31;
    const int b    = bh >> 2;
    const int h    = bh & 3;
    const int n0   = tile * 64;
    const int wv   = t >> 6;
    const int lane = t & 63;
    const int m    = lane & 15;
    const int g    = lane >> 4;

    // ---- stage w[h] -> fp16 B-frags ----
    {
        const int o  = t & 63;
        const int kc = t >> 6;
        const float* wcol = w + h * FIN * FOUT + o;
        _Float16* dst = wf + ((kc * 4 + (o >> 4)) * 512) + (o & 15) * 8;
#pragma unroll
        for (int hi = 0; hi < 4; ++hi) {
            unsigned u0 = cvt2h(wcol[(kc * 32 + hi * 8 + 0) * FOUT],
                                wcol[(kc * 32 + hi * 8 + 1) * FOUT]);
            unsigned u1 = cvt2h(wcol[(kc * 32 + hi * 8 + 2) * FOUT],
                                wcol[(kc * 32 + hi * 8 + 3) * FOUT]);
            unsigned u2 = cvt2h(wcol[(kc * 32 + hi * 8 + 4) * FOUT],
                                wcol[(kc * 32 + hi * 8 + 5) * FOUT]);
            unsigned u3 = cvt2h(wcol[(kc * 32 + hi * 8 + 6) * FOUT],
                                wcol[(kc * 32 + hi * 8 + 7) * FOUT]);
            *(uint4*)(dst + hi * 128) = uint4{u0, u1, u2, u3};
        }
    }
    // ---- stage x tile -> fp16 A-frags ----
    {
        const int r  = t >> 2;
        const int kc = t & 3;
        const float* xr = x + ((size_t)(b * NN + n0 + r)) * FIN + kc * 32;
        _Float16* dst = xf + ((r >> 4) * 16 + kc * 4) * 128 + (r & 15) * 8;
#pragma unroll
        for (int g2 = 0; g2 < 4; ++g2) {
            f32x4 va = *(const f32x4*)(xr + g2 * 8);
            f32x4 vb = *(const f32x4*)(xr + g2 * 8 + 4);
            *(uint4*)(dst + g2 * 128) = uint4{cvt2h(va[0], va[1]), cvt2h(va[2], va[3]),
                                              cvt2h(vb[0], vb[1]), cvt2h(vb[2], vb[3])};
        }
    }
    __syncthreads();

    // ---- MFMA: wave rg computes rows rg*16..+15, cols 0..63, K=128 ----
    const int rg = wv;
    f32x4 acc0 = {0,0,0,0}, acc1 = {0,0,0,0}, acc2 = {0,0,0,0}, acc3 = {0,0,0,0};
#pragma unroll
    for (int kc = 0; kc < 4; ++kc) {
        f16x8 av = *(const f16x8*)(xf + (rg * 16 + kc * 4 + g) * 128 + m * 8);
        const _Float16* wb_ = wf + kc * 4 * 512 + lane * 8;
        acc0 = __builtin_amdgcn_mfma_f32_16x16x32_f16(av, *(const f16x8*)(wb_), acc0, 0, 0, 0);
        acc1 = __builtin_amdgcn_mfma_f32_16x16x32_f16(av, *(const f16x8*)(wb_ + 512), acc1, 0, 0, 0);
        acc2 = __builtin_amdgcn_mfma_f32_16x16x32_f16(av, *(const f16x8*)(wb_ + 1024), acc2, 0, 0, 0);
        acc3 = __builtin_amdgcn_mfma_f32_16x16x32_f16(av, *(const f16x8*)(wb_ + 1536), acc3, 0, 0, 0);
    }

    // ---- epilogue: tanh -> s partials; h -> fp16 store in 32x32 frag order ----
    float s1r[4] = {0,0,0,0}, s2r[4] = {0,0,0,0};
    const int jg = n0 + rg * 16 + g * 4;     // 4 consecutive node rows
#define PROC(accX, ot)  do {                                                    \
        float asv = a_src[h * FOUT + (ot) * 16 + m];                            \
        float adv = a_dst[h * FOUT + (ot) * 16 + m];                            \
        _Pragma("unroll")                                                       \
        for (int r = 0; r < 4; ++r) {                                           \
            float th = fast_tanh(accX[r]);                                      \
            s1r[r] += th * asv;                                                 \
            s2r[r] += th * adv;                                                 \
        }                                                                       \
        unsigned u0 = cvt2h(accX[0], accX[1]);                                  \
        unsigned u1 = cvt2h(accX[2], accX[3]);                                  \
        int off = bh * 131072 + (jg >> 4) * 1024 + ((ot) >> 1) * 512            \
                + ((((ot) & 1) * 16 + m) + 32 * ((jg >> 3) & 1)) * 8 + (jg & 7);\
        *(uint2*)(h16B + off) = uint2{u0, u1};                                  \
    } while (0)
    PROC(acc0, 0); PROC(acc1, 1); PROC(acc2, 2); PROC(acc3, 3);
#undef PROC
#pragma unroll
    for (int msk = 1; msk <= 8; msk <<= 1) {
#pragma unroll
        for (int r = 0; r < 4; ++r) {
            s1r[r] += __shfl_xor(s1r[r], msk);
            s2r[r] += __shfl_xor(s2r[r], msk);
        }
    }
    if (m == 0) {
#pragma unroll
        for (int r = 0; r < 4; ++r) {
            ssrc[bh * NN + jg + r] = s1r[r] * LOG2E;
            sdst[bh * NN + jg + r] = s2r[r] * LOG2E;
        }
    }

    // ---- adj bitpack ----
    {
        const int  frow0 = bx * 16;
        const int* asrc  = adj + (size_t)frow0 * NN;
#pragma unroll
        for (int w4 = 0; w4 < 4; ++w4) {
            int widx  = t + 256 * w4;
            int row_l = widx >> 6;
            int wc    = widx & 63;
            const i32x4* p = (const i32x4*)(asrc + (size_t)row_l * NN + wc * 32);
            unsigned int wbits = 0;
#pragma unroll
            for (int k = 0; k < 8; ++k) {
                i32x4 v = p[k];
                wbits |= (unsigned int)(v[0] & 1) << (4 * k);
                wbits |= (unsigned int)(v[1] & 1) << (4 * k + 1);
                wbits |= (unsigned int)(v[2] & 1) << (4 * k + 2);
                wbits |= (unsigned int)(v[3] & 1) << (4 * k + 3);
            }
            adjbits[(size_t)(frow0 + row_l) * 64 + wc] = wbits;
        }
    }
}

// ---------------------------------------------------------------------------
// Kernel 2: masked-softmax attention + PV via 32x32x16 MFMA.
// 512 blocks (16 bh x 32 tiles of 64 rows) x 512 threads (8 waves).
// Wave (rt = wv>>2, quad = wv&3): 32 rows x its 32-j quarter of each 128-j
// step. Per step: dbuf 16KB B stage (2x global_load_lds, vmcnt(2)) |
// packed-fp16 e-gen (E-table broadcast reads) | 2 js x (2 O + 1 Z) MFMAs.
// B-frag reads shared by only 2 waves (was 4) -> LDS pipe ~halved.
// ---------------------------------------------------------------------------
__global__ __launch_bounds__(512, 4) void k2_attn(
    const unsigned int* __restrict__ adjbits,
    const _Float16* __restrict__ h16B,
    const float* __restrict__ ssrc, const float* __restrict__ sdst,
    const float* __restrict__ bias, float* __restrict__ out)
{
    // smem: [0,32K) Bf dbuf 2x16KB | [32768,+16640) adjw stride-65 |
    //       [49408,+4K) E1h | [53504,+4K) E2h | [57600,+32) redmax
    //       comb (50.2KB, stride 49) overlays [0, 50176)
    __shared__ __align__(16) char smem[57664];
    _Float16*     Bf     = (_Float16*)smem;
    unsigned int* adjw   = (unsigned int*)(smem + 32768);
    _Float16*     E1h    = (_Float16*)(smem + 49408);
    _Float16*     E2h    = (_Float16*)(smem + 53504);
    float*        redmax = (float*)(smem + 57600);
    float*        comb   = (float*)smem;

    const int t    = threadIdx.x;
    const int wv   = t >> 6;
    const int lane = t & 63;
    const int bh   = blockIdx.x >> 5;
    const int i0   = (blockIdx.x & 31) << 6;
    const int b    = bh >> 2;
    const int rt   = wv >> 2;      // row-tile of 32
    const int quad = wv & 3;       // j-quarter of each 128-j step
    const int mm   = lane & 31;    // row within tile / col within tile
    const int gg   = lane >> 5;    // k-group

    const _Float16* Bsrc = h16B + bh * 131072;

#define STAGE(bufi_, s_) do {                                                   \
    const _Float16* gs_ = Bsrc + (s_) * 8192 + t * 8;                           \
    _Float16*       ld_ = Bf + (bufi_) * 8192 + t * 8;                          \
    __builtin_amdgcn_global_load_lds(                                           \
        (const __attribute__((address_space(1))) unsigned int*)gs_,             \
        (__attribute__((address_space(3))) unsigned int*)ld_, 16, 0, 0);        \
    __builtin_amdgcn_global_load_lds(                                           \
        (const __attribute__((address_space(1))) unsigned int*)(gs_ + 4096),    \
        (__attribute__((address_space(3))) unsigned int*)(ld_ + 4096), 16, 0, 0);\
    } while (0)

    // ---- prologue ----
    STAGE(0, 0);
    // adj slab 16 KB -> stride-65 LDS (odd stride: conflict-free row reads)
    {
        const uint4* asrc = (const uint4*)(adjbits + ((size_t)b * NN + i0) * 64);
#pragma unroll
        for (int k = 0; k < 2; ++k) {
            int u   = t + 512 * k;              // uint4 index, 0..1023
            uint4 v = asrc[u];
            int row = u >> 4;
            int wc  = (u & 15) * 4;
            unsigned int* dst = adjw + row * 65 + wc;
            dst[0] = v.x; dst[1] = v.y; dst[2] = v.z; dst[3] = v.w;
        }
    }
    // fp16 E-tables + D-max
    {
        f32x4 dv = *(const f32x4*)(sdst + bh * NN + t * 4);
        *(uint2*)(E1h + t * 4) = uint2{cvt2h(fast_exp2(dv[0]), fast_exp2(dv[1])),
                                       cvt2h(fast_exp2(dv[2]), fast_exp2(dv[3]))};
        *(uint2*)(E2h + t * 4) = uint2{cvt2h(fast_exp2(0.2f * dv[0]), fast_exp2(0.2f * dv[1])),
                                       cvt2h(fast_exp2(0.2f * dv[2]), fast_exp2(0.2f * dv[3]))};
        float dm = fmaxf(fmaxf(dv[0], dv[1]), fmaxf(dv[2], dv[3]));
#pragma unroll
        for (int msk = 1; msk <= 32; msk <<= 1) dm = fmaxf(dm, __shfl_xor(dm, msk));
        if (lane == 0) redmax[wv] = dm;
    }
    asm volatile("s_waitcnt vmcnt(0)" ::: "memory");
    __syncthreads();

    float D = redmax[0];
#pragma unroll
    for (int k = 1; k < 8; ++k) D = fmaxf(D, redmax[k]);

    const int row = i0 + rt * 32 + mm;
    const float sA = ssrc[bh * NN + row];
    float c = sA + D; c = fmaxf(c, 0.2f * c);       // leaky(sA+D) >= row max logit
    const float K1f = fast_exp2(sA - c);
    const float K2f = fast_exp2(fmaf(0.2f, sA, -c));
    f16x2 K1h2; { _Float16 q = (_Float16)K1f; K1h2[0] = q; K1h2[1] = q; }
    f16x2 K2h2; { _Float16 q = (_Float16)K2f; K2h2[0] = q; K2h2[1] = q; }

    f32x16 ac0 = (f32x16)0.0f, ac1 = (f32x16)0.0f, az = (f32x16)0.0f;
    f16x8 ones;
#pragma unroll
    for (int i = 0; i < 8; ++i) ones[i] = (_Float16)1.0f;

    const int arow = (rt * 32 + mm) * 65;

#pragma unroll
    for (int s = 0; s < 16; ++s) {
        if (s < 15) {
            STAGE((s + 1) & 1, s + 1);
            asm volatile("s_waitcnt vmcnt(2)" ::: "memory");   // stage(s) done
        } else {
            asm volatile("s_waitcnt vmcnt(0)" ::: "memory");
        }
        __builtin_amdgcn_sched_barrier(0);
        __builtin_amdgcn_s_barrier();
        __builtin_amdgcn_sched_barrier(0);

        const unsigned wb = adjw[arow + s * 4 + quad];   // 32 j-bits for this row
        const int jb = s * 128 + quad * 32;
        const _Float16* bufb = Bf + (s & 1) * 8192 + (quad * 2) * 1024;

#pragma unroll
        for (int js = 0; js < 2; ++js) {
            unsigned w8 = wb >> (js * 16 + 8 * gg);
            union { f16x8 v; f16x2 p[4]; } E1u, E2u;
            union { f16x8 v; unsigned u[4]; f16x2 p[4]; } af;
            E1u.v = *(const f16x8*)(E1h + jb + js * 16 + 8 * gg);
            E2u.v = *(const f16x8*)(E2h + jb + js * 16 + 8 * gg);
#pragma unroll
            for (int p = 0; p < 4; ++p) {
                f16x2 v1 = K1h2 * E1u.p[p];
                f16x2 v2 = K2h2 * E2u.p[p];
                af.u[p] = __builtin_bit_cast(unsigned, pkmax(v1, v2)) & bmask(w8, p);
            }
            f16x8 b0 = *(const f16x8*)(bufb + js * 1024 + lane * 8);
            f16x8 b1 = *(const f16x8*)(bufb + js * 1024 + 512 + lane * 8);
            ac0 = __builtin_amdgcn_mfma_f32_32x32x16_f16(af.v, b0, ac0, 0, 0, 0);
            ac1 = __builtin_amdgcn_mfma_f32_32x32x16_f16(af.v, b1, ac1, 0, 0, 0);
            az  = __builtin_amdgcn_mfma_f32_32x32x16_f16(af.v, ones, az, 0, 0, 0);
        }

        __builtin_amdgcn_s_barrier();   // protect buf before next overwrite
    }
#undef STAGE

    // ---- combine 4 quad-partials (2-round tree; comb overlays loop smem) ----
    __syncthreads();
    if (quad & 1) {                       // quads 1,3 publish
        int slot = rt * 2 + (quad >> 1);
        float* cp = comb + (slot * 64 + lane) * 49;
#pragma unroll
        for (int r = 0; r < 16; ++r) {
            cp[r] = ac0[r]; cp[16 + r] = ac1[r]; cp[32 + r] = az[r];
        }
    }
    __syncthreads();
    if (!(quad & 1)) {                    // quads 0,2 absorb
        int slot = rt * 2 + (quad >> 1);
        const float* cp = comb + (slot * 64 + lane) * 49;
#pragma unroll
        for (int r = 0; r < 16; ++r) {
            ac0[r] += cp[r]; ac1[r] += cp[16 + r]; az[r] += cp[32 + r];
        }
    }
    __syncthreads();
    if (quad == 2) {                      // quad 2 publishes its sum
        float* cp = comb + (rt * 64 + lane) * 49;
#pragma unroll
        for (int r = 0; r < 16; ++r) {
            cp[r] = ac0[r]; cp[16 + r] = ac1[r]; cp[32 + r] = az[r];
        }
    }
    __syncthreads();
    if (quad == 0) {                      // quad 0 finishes + writes
        const float* cp = comb + (rt * 64 + lane) * 49;
        float bv0 = bias[mm];
        float bv1 = bias[32 + mm];
        size_t obase = ((size_t)bh * NN + i0 + rt * 32) * FOUT;
        // C/D layout (m74/m101): col = lane&31, row = (reg&3)+8*(reg>>2)+4*(lane>>5)
#pragma unroll
        for (int r = 0; r < 16; ++r) {
            int rowl = (r & 3) + 8 * (r >> 2) + 4 * gg;
            float z  = az[r] + cp[32 + r];
            float v0 = (ac0[r] + cp[r])      / z + bv0;
            float v1 = (ac1[r] + cp[16 + r]) / z + bv1;
            out[obase + (size_t)rowl * FOUT + mm]      = v0;
            out[obase + (size_t)rowl * FOUT + 32 + mm] = v1;
        }
    }
}

// ---------------------------------------------------------------------------
extern "C" void kernel_launch(void* const* d_in, const int* in_sizes, int n_in,
                              void* d_out, int out_size, void* d_ws, size_t ws_size,
                              hipStream_t stream) {
    (void)in_sizes; (void)n_in; (void)out_size; (void)ws_size;
    const float* x     = (const float*)d_in[0];
    const int*   adj   = (const int*)d_in[1];     // bool -> int32
    const float* w     = (const float*)d_in[2];
    const float* a_src = (const float*)d_in[3];
    const float* a_dst = (const float*)d_in[4];
    const float* bias  = (const float*)d_in[5];
    float*       out   = (float*)d_out;

    _Float16*     h16B    = (_Float16*)d_ws;                               // 4 MB
    float*        ssrc    = (float*)((char*)d_ws + 4194304);               // 128 KB
    float*        sdst    = (float*)((char*)d_ws + 4194304 + 131072);      // 128 KB
    unsigned int* adjbits = (unsigned int*)((char*)d_ws + 4718592);        // 2 MB

    k1_proj<<<512, 256, 0, stream>>>(x, w, a_src, a_dst, adj, h16B, ssrc, sdst, adjbits);
    k2_attn<<<512, 512, 0, stream>>>(adjbits, h16B, ssrc, sdst, bias, out);
}

// Round 14
// 43.056 us; speedup vs baseline: 1.0050x; 1.0050x over previous
//
#include <hip/hip_runtime.h>
#include <hip/hip_fp16.h>

#define NN   2048
#define FIN  128
#define FOUT 64
#define LOG2E 1.44269504088896f

using f16x8 = __attribute__((ext_vector_type(8))) _Float16;
using f16x4 = __attribute__((ext_vector_type(4))) _Float16;
using f16x2 = __attribute__((ext_vector_type(2))) _Float16;
using f32x4 = __attribute__((ext_vector_type(4))) float;
using i32x4 = __attribute__((ext_vector_type(4))) int;

__device__ inline float fast_exp2(float x) {
#if __has_builtin(__builtin_amdgcn_exp2f)
    return __builtin_amdgcn_exp2f(x);
#else
    return exp2f(x);
#endif
}
__device__ inline float fast_rcp(float x) {
#if __has_builtin(__builtin_amdgcn_rcpf)
    return __builtin_amdgcn_rcpf(x);
#else
    return 1.0f / x;
#endif
}
__device__ inline float fast_tanh(float x) {
    float e = fast_exp2(2.0f * LOG2E * x);
    return 1.0f - 2.0f * fast_rcp(e + 1.0f);
}
__device__ inline unsigned cvt2h(float a, float b) {
    return __builtin_bit_cast(unsigned, __builtin_amdgcn_cvt_pkrtz(a, b));
}
__device__ inline f16x2 pkmax(f16x2 a, f16x2 b) {
#if __has_builtin(__builtin_elementwise_max)
    return __builtin_elementwise_max(a, b);
#else
    f16x2 r; r[0] = a[0] > b[0] ? a[0] : b[0]; r[1] = a[1] > b[1] ? a[1] : b[1];
    return r;
#endif
}
__device__ inline unsigned bmask(unsigned wb, int p) {
    unsigned lo = (unsigned)(-(int)((wb >> (2 * p)) & 1u));
    unsigned hi = (unsigned)(-(int)((wb >> (2 * p + 1)) & 1u));
    return (hi & 0xFFFF0000u) | (lo & 0x0000FFFFu);
}

// h16B frag-ordered (16x16x32 B-frag), per (bh): halves offset =
//   bh*131072 + (j>>5)*2048 + (o>>4)*512 + (((j>>3)&3)*16 + (o&15))*8 + (j&7)
// adjbits (ROW-MAJOR dense): [flat_row(8192)][wc(64)] u32

// ---------------------------------------------------------------------------
// Kernel 1: identical to R12 (MFMA projection + fast-tanh + bitpack).
// ---------------------------------------------------------------------------
__global__ __launch_bounds__(256) void k1_proj(
    const float* __restrict__ x, const float* __restrict__ w,
    const float* __restrict__ a_src, const float* __restrict__ a_dst,
    const int* __restrict__ adj,
    _Float16* __restrict__ h16B, float* __restrict__ ssrc, float* __restrict__ sdst,
    unsigned int* __restrict__ adjbits)
{
    __shared__ __align__(16) _Float16 xf[8192];
    __shared__ __align__(16) _Float16 wf[8192];

    const int t    = threadIdx.x;
    const int bx   = blockIdx.x;
    const int bh   = bx >> 5;
    const int tile = bx & 31;
    const int b    = bh >> 2;
    const int h    = bh & 3;
    const int n0   = tile * 64;
    const int wv   = t >> 6;
    const int lane = t & 63;
    const int m    = lane & 15;
    const int g    = lane >> 4;

    {
        const int o  = t & 63;
        const int kc = t >> 6;
        const float* wcol = w + h * FIN * FOUT + o;
        _Float16* dst = wf + ((kc * 4 + (o >> 4)) * 512) + (o & 15) * 8;
#pragma unroll
        for (int hi = 0; hi < 4; ++hi) {
            unsigned u0 = cvt2h(wcol[(kc * 32 + hi * 8 + 0) * FOUT],
                                wcol[(kc * 32 + hi * 8 + 1) * FOUT]);
            unsigned u1 = cvt2h(wcol[(kc * 32 + hi * 8 + 2) * FOUT],
                                wcol[(kc * 32 + hi * 8 + 3) * FOUT]);
            unsigned u2 = cvt2h(wcol[(kc * 32 + hi * 8 + 4) * FOUT],
                                wcol[(kc * 32 + hi * 8 + 5) * FOUT]);
            unsigned u3 = cvt2h(wcol[(kc * 32 + hi * 8 + 6) * FOUT],
                                wcol[(kc * 32 + hi * 8 + 7) * FOUT]);
            *(uint4*)(dst + hi * 128) = uint4{u0, u1, u2, u3};
        }
    }
    {
        const int r  = t >> 2;
        const int kc = t & 3;
        const float* xr = x + ((size_t)(b * NN + n0 + r)) * FIN + kc * 32;
        _Float16* dst = xf + ((r >> 4) * 16 + kc * 4) * 128 + (r & 15) * 8;
#pragma unroll
        for (int g2 = 0; g2 < 4; ++g2) {
            f32x4 va = *(const f32x4*)(xr + g2 * 8);
            f32x4 vb = *(const f32x4*)(xr + g2 * 8 + 4);
            *(uint4*)(dst + g2 * 128) = uint4{cvt2h(va[0], va[1]), cvt2h(va[2], va[3]),
                                              cvt2h(vb[0], vb[1]), cvt2h(vb[2], vb[3])};
        }
    }
    __syncthreads();

    const int rg = wv;
    f32x4 acc0 = {0,0,0,0}, acc1 = {0,0,0,0}, acc2 = {0,0,0,0}, acc3 = {0,0,0,0};
#pragma unroll
    for (int kc = 0; kc < 4; ++kc) {
        f16x8 av = *(const f16x8*)(xf + (rg * 16 + kc * 4 + g) * 128 + m * 8);
        const _Float16* wb_ = wf + kc * 4 * 512 + lane * 8;
        acc0 = __builtin_amdgcn_mfma_f32_16x16x32_f16(av, *(const f16x8*)(wb_), acc0, 0, 0, 0);
        acc1 = __builtin_amdgcn_mfma_f32_16x16x32_f16(av, *(const f16x8*)(wb_ + 512), acc1, 0, 0, 0);
        acc2 = __builtin_amdgcn_mfma_f32_16x16x32_f16(av, *(const f16x8*)(wb_ + 1024), acc2, 0, 0, 0);
        acc3 = __builtin_amdgcn_mfma_f32_16x16x32_f16(av, *(const f16x8*)(wb_ + 1536), acc3, 0, 0, 0);
    }

    float s1r[4] = {0,0,0,0}, s2r[4] = {0,0,0,0};
    const int jg = n0 + rg * 16 + g * 4;
#define PROC(accX, ot)  do {                                                    \
        float asv = a_src[h * FOUT + (ot) * 16 + m];                            \
        float adv = a_dst[h * FOUT + (ot) * 16 + m];                            \
        _Pragma("unroll")                                                       \
        for (int r = 0; r < 4; ++r) {                                           \
            float th = fast_tanh(accX[r]);                                      \
            s1r[r] += th * asv;                                                 \
            s2r[r] += th * adv;                                                 \
        }                                                                       \
        unsigned u0 = cvt2h(accX[0], accX[1]);                                  \
        unsigned u1 = cvt2h(accX[2], accX[3]);                                  \
        int off = bh * 131072 + (jg >> 5) * 2048 + (ot) * 512                   \
                + (((jg >> 3) & 3) * 16 + m) * 8 + (jg & 7);                    \
        *(uint2*)(h16B + off) = uint2{u0, u1};                                  \
    } while (0)
    PROC(acc0, 0); PROC(acc1, 1); PROC(acc2, 2); PROC(acc3, 3);
#undef PROC
#pragma unroll
    for (int msk = 1; msk <= 8; msk <<= 1) {
#pragma unroll
        for (int r = 0; r < 4; ++r) {
            s1r[r] += __shfl_xor(s1r[r], msk);
            s2r[r] += __shfl_xor(s2r[r], msk);
        }
    }
    if (m == 0) {
#pragma unroll
        for (int r = 0; r < 4; ++r) {
            ssrc[bh * NN + jg + r] = s1r[r] * LOG2E;
            sdst[bh * NN + jg + r] = s2r[r] * LOG2E;
        }
    }

    {
        const int  frow0 = bx * 16;
        const int* asrc  = adj + (size_t)frow0 * NN;
#pragma unroll
        for (int w4 = 0; w4 < 4; ++w4) {
            int widx  = t + 256 * w4;
            int row_l = widx >> 6;
            int wc    = widx & 63;
            const i32x4* p = (const i32x4*)(asrc + (size_t)row_l * NN + wc * 32);
            unsigned int wbits = 0;
#pragma unroll
            for (int k = 0; k < 8; ++k) {
                i32x4 v = p[k];
                wbits |= (unsigned int)(v[0] & 1) << (4 * k);
                wbits |= (unsigned int)(v[1] & 1) << (4 * k + 1);
                wbits |= (unsigned int)(v[2] & 1) << (4 * k + 2);
                wbits |= (unsigned int)(v[3] & 1) << (4 * k + 3);
            }
            adjbits[(size_t)(frow0 + row_l) * 64 + wc] = wbits;
        }
    }
}

// ---------------------------------------------------------------------------
// Kernel 2: R12 structure, 128-row tiles (256 blocks = 1/CU), 8 waves.
// Wave (rgp = wv>>1, par = wv&1): row-groups rgA=2rgp, rgB=2rgp+1 (32 rows)
// x j-half par. B-frags + E-reads shared across both rgs -> per-row LDS
// instruction count halved vs R12. Packed-fp16 e-gen, full unroll, dbuf
// stage with counted vmcnt(1). LDS 59.4 KB.
// ---------------------------------------------------------------------------
__global__ __launch_bounds__(512, 2) void k2_attn(
    const unsigned int* __restrict__ adjbits,
    const _Float16* __restrict__ h16B,
    const float* __restrict__ ssrc, const float* __restrict__ sdst,
    const float* __restrict__ bias, float* __restrict__ out)
{
    // smem: [0,16K) Bf dbuf 2x8KB | [16384,+34816) adjw 128x68 | [51200,+4K) E1h
    //       | [55296,+4K) E2h | [59392,+32) redmax. comb (42KB, stride 41)
    //       overlays [0, 41984).
    __shared__ __align__(16) char smem[59424];
    _Float16*     Bf     = (_Float16*)smem;
    unsigned int* adjw   = (unsigned int*)(smem + 16384);  // stride 68 words
    _Float16*     E1h    = (_Float16*)(smem + 51200);
    _Float16*     E2h    = (_Float16*)(smem + 55296);
    float*        redmax = (float*)(smem + 59392);
    float*        comb   = (float*)smem;

    const int t    = threadIdx.x;
    const int wv   = t >> 6;
    const int lane = t & 63;
    const int bh   = blockIdx.x >> 4;
    const int i0   = (blockIdx.x & 15) << 7;    // 128-row tile
    const int b    = bh >> 2;
    const int rgp  = wv >> 1;
    const int par  = wv & 1;
    const int m    = lane & 15;
    const int g    = lane >> 4;
    const int rgA  = rgp * 2;
    const int rgB  = rgp * 2 + 1;

    const _Float16* Bsrc = h16B + bh * 131072;

#define STAGE(bufi_, s_)                                                        \
    __builtin_amdgcn_global_load_lds(                                           \
        (const __attribute__((address_space(1))) unsigned int*)(Bsrc + (s_) * 4096 + t * 8), \
        (__attribute__((address_space(3))) unsigned int*)(Bf + (bufi_) * 4096 + t * 8), \
        16, 0, 0)

    STAGE(0, 0);
    // adj slab 32 KB (128 rows) -> stride-68 LDS
    {
        const uint4* asrc = (const uint4*)(adjbits + ((size_t)b * NN + i0) * 64);
#pragma unroll
        for (int k = 0; k < 4; ++k) {
            int idx = t + 512 * k;                 // 0..2047 uint4; 16 per row
            uint4 v = asrc[idx];
            *(uint4*)(adjw + (idx >> 4) * 68 + (idx & 15) * 4) = v;
        }
    }
    // fp16 E-tables + D-max
    {
        f32x4 dv = *(const f32x4*)(sdst + bh * NN + t * 4);
        *(uint2*)(E1h + t * 4) = uint2{cvt2h(fast_exp2(dv[0]), fast_exp2(dv[1])),
                                       cvt2h(fast_exp2(dv[2]), fast_exp2(dv[3]))};
        *(uint2*)(E2h + t * 4) = uint2{cvt2h(fast_exp2(0.2f * dv[0]), fast_exp2(0.2f * dv[1])),
                                       cvt2h(fast_exp2(0.2f * dv[2]), fast_exp2(0.2f * dv[3]))};
        float dm = fmaxf(fmaxf(dv[0], dv[1]), fmaxf(dv[2], dv[3]));
#pragma unroll
        for (int msk = 1; msk <= 32; msk <<= 1) dm = fmaxf(dm, __shfl_xor(dm, msk));
        if (lane == 0) redmax[wv] = dm;
    }
    asm volatile("s_waitcnt vmcnt(0)" ::: "memory");
    __syncthreads();

    float D = redmax[0];
#pragma unroll
    for (int k = 1; k < 8; ++k) D = fmaxf(D, redmax[k]);

    const float sA_a = ssrc[bh * NN + i0 + rgA * 16 + m];
    const float sA_b = ssrc[bh * NN + i0 + rgB * 16 + m];
    float c_a = sA_a + D; c_a = fmaxf(c_a, 0.2f * c_a);
    float c_b = sA_b + D; c_b = fmaxf(c_b, 0.2f * c_b);
    const float K1a = fast_exp2(sA_a - c_a);
    const float K2a = fast_exp2(fmaf(0.2f, sA_a, -c_a));
    const float K1b = fast_exp2(sA_b - c_b);
    const float K2b = fast_exp2(fmaf(0.2f, sA_b, -c_b));
    f16x2 K1a2, K2a2, K1b2, K2b2;
    { _Float16 q = (_Float16)K1a; K1a2[0] = q; K1a2[1] = q; }
    { _Float16 q = (_Float16)K2a; K2a2[0] = q; K2a2[1] = q; }
    { _Float16 q = (_Float16)K1b; K1b2[0] = q; K1b2[1] = q; }
    { _Float16 q = (_Float16)K2b; K2b2[0] = q; K2b2[1] = q; }

    f32x4 aA0 = {0,0,0,0}, aA1 = {0,0,0,0}, aA2 = {0,0,0,0}, aA3 = {0,0,0,0};
    f32x4 aB0 = {0,0,0,0}, aB1 = {0,0,0,0}, aB2 = {0,0,0,0}, aB3 = {0,0,0,0};
    f32x4 zA = {0,0,0,0}, zB = {0,0,0,0};
    f16x8 ones;
#pragma unroll
    for (int i = 0; i < 8; ++i) ones[i] = (_Float16)1.0f;

    const int arowA = (rgA * 16 + m) * 68;
    const int arowB = (rgB * 16 + m) * 68;

#pragma unroll
    for (int s = 0; s < 32; ++s) {
        if (s < 31) {
            STAGE((s + 1) & 1, s + 1);
            asm volatile("s_waitcnt vmcnt(1)" ::: "memory");
        } else {
            asm volatile("s_waitcnt vmcnt(0)" ::: "memory");
        }
        __builtin_amdgcn_sched_barrier(0);
        __builtin_amdgcn_s_barrier();
        __builtin_amdgcn_sched_barrier(0);

        const int ci = 2 * s + par;
        unsigned wbA = adjw[arowA + ci] >> (8 * g);
        unsigned wbB = adjw[arowB + ci] >> (8 * g);
        union { f16x8 v; f16x2 p[4]; unsigned u[4]; } E1u, E2u, afA, afB;
        E1u.v = *(const f16x8*)(E1h + ci * 32 + 8 * g);
        E2u.v = *(const f16x8*)(E2h + ci * 32 + 8 * g);

        const _Float16* bb = Bf + (s & 1) * 4096 + par * 2048 + lane * 8;
        f16x8 b0 = *(const f16x8*)(bb);
        f16x8 b1 = *(const f16x8*)(bb + 512);
        f16x8 b2 = *(const f16x8*)(bb + 1024);
        f16x8 b3 = *(const f16x8*)(bb + 1536);

#pragma unroll
        for (int p = 0; p < 4; ++p) {
            f16x2 e1 = E1u.p[p];
            f16x2 e2 = E2u.p[p];
            afA.u[p] = __builtin_bit_cast(unsigned, pkmax(K1a2 * e1, K2a2 * e2)) & bmask(wbA, p);
            afB.u[p] = __builtin_bit_cast(unsigned, pkmax(K1b2 * e1, K2b2 * e2)) & bmask(wbB, p);
        }

        aA0 = __builtin_amdgcn_mfma_f32_16x16x32_f16(afA.v, b0, aA0, 0, 0, 0);
        aA1 = __builtin_amdgcn_mfma_f32_16x16x32_f16(afA.v, b1, aA1, 0, 0, 0);
        aA2 = __builtin_amdgcn_mfma_f32_16x16x32_f16(afA.v, b2, aA2, 0, 0, 0);
        aA3 = __builtin_amdgcn_mfma_f32_16x16x32_f16(afA.v, b3, aA3, 0, 0, 0);
        zA  = __builtin_amdgcn_mfma_f32_16x16x32_f16(afA.v, ones, zA, 0, 0, 0);
        aB0 = __builtin_amdgcn_mfma_f32_16x16x32_f16(afB.v, b0, aB0, 0, 0, 0);
        aB1 = __builtin_amdgcn_mfma_f32_16x16x32_f16(afB.v, b1, aB1, 0, 0, 0);
        aB2 = __builtin_amdgcn_mfma_f32_16x16x32_f16(afB.v, b2, aB2, 0, 0, 0);
        aB3 = __builtin_amdgcn_mfma_f32_16x16x32_f16(afB.v, b3, aB3, 0, 0, 0);
        zB  = __builtin_amdgcn_mfma_f32_16x16x32_f16(afB.v, ones, zB, 0, 0, 0);

        __builtin_amdgcn_s_barrier();
    }
#undef STAGE

    // ---- combine parity partials (comb overlays loop smem; stride 41) ----
    __syncthreads();
    if (par == 1) {
        float* cp = comb + (rgp * 64 + lane) * 41;
#pragma unroll
        for (int r = 0; r < 4; ++r) {
            cp[0 + r]  = aA0[r]; cp[4 + r]  = aA1[r];
            cp[8 + r]  = aA2[r]; cp[12 + r] = aA3[r];
            cp[16 + r] = zA[r];
            cp[20 + r] = aB0[r]; cp[24 + r] = aB1[r];
            cp[28 + r] = aB2[r]; cp[32 + r] = aB3[r];
            cp[36 + r] = zB[r];
        }
    }
    __syncthreads();
    if (par == 0) {
        const float* cp = comb + (rgp * 64 + lane) * 41;
        float zsA[4], zsB[4];
#pragma unroll
        for (int r = 0; r < 4; ++r) {
            zsA[r] = zA[r] + cp[16 + r];
            zsB[r] = zB[r] + cp[36 + r];
        }
        size_t obaseA = ((size_t)bh * NN + i0 + rgA * 16) * FOUT;
        size_t obaseB = ((size_t)bh * NN + i0 + rgB * 16) * FOUT;
        // C/D layout: col = lane&15, row = g*4 + r
#pragma unroll
        for (int ot = 0; ot < 4; ++ot) {
            float bv = bias[ot * 16 + m];
            f32x4 aA = (ot == 0) ? aA0 : (ot == 1) ? aA1 : (ot == 2) ? aA2 : aA3;
            f32x4 aB = (ot == 0) ? aB0 : (ot == 1) ? aB1 : (ot == 2) ? aB2 : aB3;
#pragma unroll
            for (int r = 0; r < 4; ++r) {
                float vA = (aA[r] + cp[ot * 4 + r])      / zsA[r] + bv;
                float vB = (aB[r] + cp[20 + ot * 4 + r]) / zsB[r] + bv;
                out[obaseA + (size_t)(g * 4 + r) * FOUT + ot * 16 + m] = vA;
                out[obaseB + (size_t)(g * 4 + r) * FOUT + ot * 16 + m] = vB;
            }
        }
    }
}

// ---------------------------------------------------------------------------
extern "C" void kernel_launch(void* const* d_in, const int* in_sizes, int n_in,
                              void* d_out, int out_size, void* d_ws, size_t ws_size,
                              hipStream_t stream) {
    (void)in_sizes; (void)n_in; (void)out_size; (void)ws_size;
    const float* x     = (const float*)d_in[0];
    const int*   adj   = (const int*)d_in[1];     // bool -> int32
    const float* w     = (const float*)d_in[2];
    const float* a_src = (const float*)d_in[3];
    const float* a_dst = (const float*)d_in[4];
    const float* bias  = (const float*)d_in[5];
    float*       out   = (float*)d_out;

    _Float16*     h16B    = (_Float16*)d_ws;                               // 4 MB
    float*        ssrc    = (float*)((char*)d_ws + 4194304);               // 128 KB
    float*        sdst    = (float*)((char*)d_ws + 4194304 + 131072);      // 128 KB
    unsigned int* adjbits = (unsigned int*)((char*)d_ws + 4718592);        // 2 MB

    k1_proj<<<512, 256, 0, stream>>>(x, w, a_src, a_dst, adj, h16B, ssrc, sdst, adjbits);
    k2_attn<<<256, 512, 0, stream>>>(adjbits, h16B, ssrc, sdst, bias, out);
}